// Round 4
// baseline (256.237 us; speedup 1.0000x reference)
//
#include <hip/hip_runtime.h>
#include <hip/hip_bf16.h>

#define S_ 512
#define B_ 32
#define D_ 1024
#define F_ 1024

typedef float f32x4 __attribute__((ext_vector_type(4)));
typedef short bf16x8 __attribute__((ext_vector_type(8)));

static __device__ __forceinline__ unsigned short f2bf(float f) {
    __hip_bfloat16 h = __float2bfloat16(f);
    return *reinterpret_cast<unsigned short*>(&h);
}

static __device__ __forceinline__ float sigmoidf_fast(float x) {
    float e = __builtin_amdgcn_exp2f(x * -1.44269504088896f);
    return __builtin_amdgcn_rcpf(1.0f + e);
}

// ---------------- Kernel V: v = x0 @ [w1|w2]^T + bias, into vbuf[B][2048] ----
__global__ __launch_bounds__(256) void vker(
    const float* __restrict__ x,
    const float* __restrict__ w1w, const float* __restrict__ w1b,
    const float* __restrict__ w2w, const float* __restrict__ w2b,
    float* __restrict__ vbuf)
{
    __shared__ float xs[B_][132];
    __shared__ float wst[64][132];
    int fb = blockIdx.x & 31;
    int ks = blockIdx.x >> 5;
    int k0 = ks * 128;
    int t  = threadIdx.x;
    const float* w = (fb < 16) ? w1w : w2w;
    int fbase = (fb < 16) ? fb * 64 : (fb - 16) * 64;

    #pragma unroll
    for (int i = 0; i < 4; ++i) {
        int q = t + 256 * i;
        int row = q >> 5, c4 = (q & 31) * 4;
        float4 v = *reinterpret_cast<const float4*>(x + (size_t)row * D_ + k0 + c4);
        *reinterpret_cast<float4*>(&xs[row][c4]) = v;
    }
    #pragma unroll
    for (int i = 0; i < 8; ++i) {
        int q = t + 256 * i;
        int row = q >> 5, c4 = (q & 31) * 4;
        float4 v = *reinterpret_cast<const float4*>(w + (size_t)(fbase + row) * D_ + k0 + c4);
        *reinterpret_cast<float4*>(&wst[row][c4]) = v;
    }
    __syncthreads();

    int b   = t >> 3;
    int fl0 = t & 7;
    float acc[8] = {0,0,0,0,0,0,0,0};
    for (int k4 = 0; k4 < 32; ++k4) {
        float4 xv = *reinterpret_cast<const float4*>(&xs[b][k4 * 4]);
        #pragma unroll
        for (int j = 0; j < 8; ++j) {
            float4 wv = *reinterpret_cast<const float4*>(&wst[fl0 + 8 * j][k4 * 4]);
            acc[j] += xv.x * wv.x + xv.y * wv.y + xv.z * wv.z + xv.w * wv.w;
        }
    }
    #pragma unroll
    for (int j = 0; j < 8; ++j) {
        int fg = fb * 64 + fl0 + 8 * j;
        float v = acc[j];
        if (ks == 0) v += (fg < 1024) ? w1b[fg] : w2b[fg - 1024];
        atomicAdd(&vbuf[b * 2048 + fg], v);
    }
}

// ---------------- fused: out[s,b,f] = sum_d x*sigmoid(v1*v2)*mw + mb --------
// block = (b, f-tile of 128, s-half of 256); 512 threads = 8 waves (4s x 2f).
// Per K-tile (BK=64): reg-stage A (f32->bf16) and B (sigmoid mask) into
// XOR-swizzled LDS (slot ^= row&7 on 16B chunks of the 128B row).
__global__ __launch_bounds__(512) void fused(
    const float* __restrict__ x, const float* __restrict__ mw,
    const float* __restrict__ mb, const float* __restrict__ vbuf,
    float* __restrict__ out)
{
    __shared__ __align__(16) unsigned short As[256 * 64];   // [s-row][64d] swizzled
    __shared__ __align__(16) unsigned short Bs[128 * 64];   // [f-row][64d] swizzled
    __shared__ float v2s[128];

    const int bid = blockIdx.x;
    // XCD swizzle: all 16 blocks of batch b land on XCD (b&7), assuming xcd=bid%8
    const int b   = (bid & 7) + ((bid >> 3) & 3) * 8;
    const int rem = bid >> 5;                   // 0..15
    const int f0  = (rem & 7) * 128;
    const int s0  = (rem >> 3) * 256;

    const int tid  = threadIdx.x;
    const int lane = tid & 63, wid = tid >> 6;
    const int wr = (wid >> 1) * 64;             // s-offset of wave in 256
    const int wc = (wid & 1) * 64;              // f-offset of wave in 128

    if (tid < 128) v2s[tid] = vbuf[b * 2048 + 1024 + f0 + tid];

    // staging coords
    const int arow = tid >> 1;                  // s-row 0..255
    const int adc  = (tid & 1) * 32;            // d-offset within K-tile
    const float* ap = x + (size_t)(s0 + arow) * (B_ * D_) + (size_t)b * D_ + adc;
    const int brow = tid >> 2;                  // f-row 0..127
    const int bdc  = (tid & 3) * 16;
    const float* wp = mw + (size_t)(f0 + brow) * D_ + bdc;
    const float* vp = vbuf + b * 2048 + bdc;

    unsigned short* Abase = As + arow * 64;
    unsigned short* Bbase = Bs + brow * 64;
    const int aswz = arow & 7, bswz = brow & 7;
    const int acb  = adc >> 3;                  // 0 or 4
    const int bcb  = bdc >> 3;                  // 0,2,4,6

    f32x4 acc[4][4] = {};
    float4 av[8], wv[4], v1v[4];

#define LOADS(K0) do { \
    _Pragma("unroll") for (int i = 0; i < 8; ++i) \
        av[i] = *reinterpret_cast<const float4*>(ap + (K0) + i * 4); \
    _Pragma("unroll") for (int i = 0; i < 4; ++i) { \
        wv[i]  = *reinterpret_cast<const float4*>(wp + (K0) + i * 4); \
        v1v[i] = *reinterpret_cast<const float4*>(vp + (K0) + i * 4); } \
} while (0)

    LOADS(0);
    // make v2s store visible before any wave's first B-write reads it
    asm volatile("s_waitcnt lgkmcnt(0)" ::: "memory");

    for (int kt = 0; kt < 16; ++kt) {
        __builtin_amdgcn_s_barrier();           // prev MFMA done reading LDS
        // ---- A write: f32 -> bf16, swizzled 16B chunks
        #pragma unroll
        for (int j = 0; j < 4; ++j) {
            union { unsigned short u[8]; bf16x8 v; } p;
            float4 lo = av[2 * j], hi = av[2 * j + 1];
            p.u[0] = f2bf(lo.x); p.u[1] = f2bf(lo.y);
            p.u[2] = f2bf(lo.z); p.u[3] = f2bf(lo.w);
            p.u[4] = f2bf(hi.x); p.u[5] = f2bf(hi.y);
            p.u[6] = f2bf(hi.z); p.u[7] = f2bf(hi.w);
            *reinterpret_cast<bf16x8*>(Abase + (((acb + j) ^ aswz) << 3)) = p.v;
        }
        // ---- B write: mask = sigmoid(v1*v2)*mw -> bf16, swizzled
        {
            float v2 = v2s[brow];
            #pragma unroll
            for (int j = 0; j < 2; ++j) {
                union { unsigned short u[8]; bf16x8 v; } p;
                float4 va = v1v[2 * j], vb = v1v[2 * j + 1];
                float4 wa = wv[2 * j],  wb = wv[2 * j + 1];
                p.u[0] = f2bf(sigmoidf_fast(va.x * v2) * wa.x);
                p.u[1] = f2bf(sigmoidf_fast(va.y * v2) * wa.y);
                p.u[2] = f2bf(sigmoidf_fast(va.z * v2) * wa.z);
                p.u[3] = f2bf(sigmoidf_fast(va.w * v2) * wa.w);
                p.u[4] = f2bf(sigmoidf_fast(vb.x * v2) * wb.x);
                p.u[5] = f2bf(sigmoidf_fast(vb.y * v2) * wb.y);
                p.u[6] = f2bf(sigmoidf_fast(vb.z * v2) * wb.z);
                p.u[7] = f2bf(sigmoidf_fast(vb.w * v2) * wb.w);
                *reinterpret_cast<bf16x8*>(Bbase + (((bcb + j) ^ bswz) << 3)) = p.v;
            }
        }
        if (kt < 15) LOADS((kt + 1) * 64);      // in flight across compute phase
        asm volatile("s_waitcnt lgkmcnt(0)" ::: "memory");
        __builtin_amdgcn_s_barrier();           // writes visible to all waves
        // ---- compute
        #pragma unroll
        for (int kh = 0; kh < 2; ++kh) {
            const int kslot = (lane >> 4) + kh * 4;
            bf16x8 af[4], bq[4];
            #pragma unroll
            for (int m2 = 0; m2 < 4; ++m2) {
                int r = wr + m2 * 16 + (lane & 15);
                af[m2] = *reinterpret_cast<const bf16x8*>(
                    As + r * 64 + ((kslot ^ (r & 7)) << 3));
            }
            #pragma unroll
            for (int n2 = 0; n2 < 4; ++n2) {
                int r = wc + n2 * 16 + (lane & 15);
                bq[n2] = *reinterpret_cast<const bf16x8*>(
                    Bs + r * 64 + ((kslot ^ (r & 7)) << 3));
            }
            #pragma unroll
            for (int m2 = 0; m2 < 4; ++m2)
                #pragma unroll
                for (int n2 = 0; n2 < 4; ++n2)
                    acc[m2][n2] = __builtin_amdgcn_mfma_f32_16x16x32_bf16(
                        af[m2], bq[n2], acc[m2][n2], 0, 0, 0);
        }
    }
#undef LOADS

    // epilogue: C/D layout col=lane&15 (f), row=(lane>>4)*4+r (s)
    const int col = lane & 15, rg = (lane >> 4) * 4;
    float bias[4];
    #pragma unroll
    for (int n2 = 0; n2 < 4; ++n2) bias[n2] = mb[f0 + wc + n2 * 16 + col];
    #pragma unroll
    for (int m2 = 0; m2 < 4; ++m2)
        #pragma unroll
        for (int n2 = 0; n2 < 4; ++n2)
            #pragma unroll
            for (int r = 0; r < 4; ++r) {
                int srow = s0 + wr + m2 * 16 + rg + r;
                out[(size_t)srow * (B_ * F_) + b * F_ + f0 + wc + n2 * 16 + col]
                    = acc[m2][n2][r] + bias[n2];
            }
}

extern "C" void kernel_launch(void* const* d_in, const int* in_sizes, int n_in,
                              void* d_out, int out_size, void* d_ws, size_t ws_size,
                              hipStream_t stream) {
    const float* x   = (const float*)d_in[0];
    const float* w1w = (const float*)d_in[1];
    const float* w1b = (const float*)d_in[2];
    const float* w2w = (const float*)d_in[3];
    const float* w2b = (const float*)d_in[4];
    const float* mw  = (const float*)d_in[5];
    const float* mb  = (const float*)d_in[6];
    float* outp = (float*)d_out;
    float* vbuf = (float*)d_ws;                 // [32][2048] f32 = 256 KB

    hipMemsetAsync(vbuf, 0, B_ * 2048 * sizeof(float), stream);
    vker<<<256, 256, 0, stream>>>(x, w1w, w1b, w2w, w2b, vbuf);
    fused<<<512, 512, 0, stream>>>(x, mw, mb, vbuf, outp);
}

// Round 6
// 213.876 us; speedup vs baseline: 1.1981x; 1.1981x over previous
//
#include <hip/hip_runtime.h>
#include <hip/hip_bf16.h>

#define S_ 512
#define B_ 32
#define D_ 1024
#define F_ 1024
#define XSTRIDE (B_ * D_)   // 32768 floats between consecutive s rows

typedef float f32x4 __attribute__((ext_vector_type(4)));
typedef short bf16x8 __attribute__((ext_vector_type(8)));

static __device__ __forceinline__ unsigned short f2bf(float f) {
    __hip_bfloat16 h = __float2bfloat16(f);
    return *reinterpret_cast<unsigned short*>(&h);
}

// ---------------- Kernel V: v = x0 @ [w1|w2]^T + bias, into vbuf[B][2048] ----
// v1 half (fg<1024) is pre-scaled by -log2(e) so fused can use exp2 directly.
__global__ __launch_bounds__(256) void vker(
    const float* __restrict__ x,
    const float* __restrict__ w1w, const float* __restrict__ w1b,
    const float* __restrict__ w2w, const float* __restrict__ w2b,
    float* __restrict__ vbuf)
{
    __shared__ float xs[B_][132];
    __shared__ float wst[64][132];
    int fb = blockIdx.x & 31;
    int ks = blockIdx.x >> 5;
    int k0 = ks * 128;
    int t  = threadIdx.x;
    const float* w = (fb < 16) ? w1w : w2w;
    int fbase = (fb < 16) ? fb * 64 : (fb - 16) * 64;

    #pragma unroll
    for (int i = 0; i < 4; ++i) {
        int q = t + 256 * i;
        int row = q >> 5, c4 = (q & 31) * 4;
        float4 v = *reinterpret_cast<const float4*>(x + (size_t)row * D_ + k0 + c4);
        *reinterpret_cast<float4*>(&xs[row][c4]) = v;
    }
    #pragma unroll
    for (int i = 0; i < 8; ++i) {
        int q = t + 256 * i;
        int row = q >> 5, c4 = (q & 31) * 4;
        float4 v = *reinterpret_cast<const float4*>(w + (size_t)(fbase + row) * D_ + k0 + c4);
        *reinterpret_cast<float4*>(&wst[row][c4]) = v;
    }
    __syncthreads();

    int b   = t >> 3;
    int fl0 = t & 7;
    float acc[8] = {0,0,0,0,0,0,0,0};
    for (int k4 = 0; k4 < 32; ++k4) {
        float4 xv = *reinterpret_cast<const float4*>(&xs[b][k4 * 4]);
        #pragma unroll
        for (int j = 0; j < 8; ++j) {
            float4 wv = *reinterpret_cast<const float4*>(&wst[fl0 + 8 * j][k4 * 4]);
            acc[j] += xv.x * wv.x + xv.y * wv.y + xv.z * wv.z + xv.w * wv.w;
        }
    }
    #pragma unroll
    for (int j = 0; j < 8; ++j) {
        int fg = fb * 64 + fl0 + 8 * j;
        float v = acc[j];
        if (ks == 0) v += (fg < 1024) ? w1b[fg] : w2b[fg - 1024];
        if (fg < 1024) v *= -1.44269504088896f;   // fold -log2(e) into v1
        atomicAdd(&vbuf[b * 2048 + fg], v);
    }
}

// ---------------- fused: out[s,b,f] = sum_d x*sigmoid(v1*v2)*mw + mb --------
// block = (b, f-tile 128, s-half 256); 512 threads = 8 waves (4s x 2f).
// Staging: c8 = tid&7 (16B chunk), rbase = tid>>3 -> each 8-lane group reads
// 256B contiguous of one row; lanes read 32B contiguous each (coalesced).
__global__ __launch_bounds__(512) void fused(
    const float* __restrict__ x, const float* __restrict__ mw,
    const float* __restrict__ mb, const float* __restrict__ vbuf,
    float* __restrict__ out)
{
    __shared__ __align__(16) unsigned short As[256 * 64];   // swizzled [s][d]
    __shared__ __align__(16) unsigned short Bs[128 * 64];   // swizzled [f][d]
    __shared__ float v2s[128];

    const int bid = blockIdx.x;
    // XCD swizzle (xcd = bid % 8): 64 blocks/XCD = 4 batches x 16 tiles
    const int b   = (bid & 7) + ((bid >> 3) & 3) * 8;
    const int rem = bid >> 5;                   // 0..15
    const int f0  = (rem & 7) * 128;
    const int s0  = (rem >> 3) * 256;

    const int tid  = threadIdx.x;
    const int lane = tid & 63, wid = tid >> 6;
    const int wr = (wid >> 1) * 64;             // wave s-offset
    const int wc = (wid & 1) * 64;              // wave f-offset

    if (tid < 128) v2s[tid] = vbuf[b * 2048 + 1024 + f0 + tid];

    const int rbase = tid >> 3;                 // 0..63
    const int c8    = tid & 7;                  // which 8-float chunk of 64
    const int wchunk = ((c8 ^ (rbase & 7)) << 3);

    const float* apt = x  + (size_t)(s0 + rbase) * XSTRIDE + (size_t)b * D_ + c8 * 8;
    const float* wpt = mw + (size_t)(f0 + rbase) * D_ + c8 * 8;
    const float* vpt = vbuf + b * 2048 + c8 * 8;

    unsigned short* Awr = As + rbase * 64 + wchunk;
    unsigned short* Bwr = Bs + rbase * 64 + wchunk;

    f32x4 acc[4][4] = {};
    float4 a[4][2], w[2][2], vv[2];

#define LOADS(K0) do { \
    _Pragma("unroll") for (int p = 0; p < 4; ++p) { \
        a[p][0] = *reinterpret_cast<const float4*>(apt + (size_t)p * (64 * XSTRIDE) + (K0)); \
        a[p][1] = *reinterpret_cast<const float4*>(apt + (size_t)p * (64 * XSTRIDE) + (K0) + 4); } \
    _Pragma("unroll") for (int p = 0; p < 2; ++p) { \
        w[p][0] = *reinterpret_cast<const float4*>(wpt + p * (64 * D_) + (K0)); \
        w[p][1] = *reinterpret_cast<const float4*>(wpt + p * (64 * D_) + (K0) + 4); } \
    vv[0] = *reinterpret_cast<const float4*>(vpt + (K0)); \
    vv[1] = *reinterpret_cast<const float4*>(vpt + (K0) + 4); \
} while (0)

    LOADS(0);
    __syncthreads();                            // v2s visible to all waves
    const float v2r0 = v2s[rbase];
    const float v2r1 = v2s[rbase + 64];

    for (int kt = 0; kt < 16; ++kt) {
        // ---- A write: f32 -> bf16, one ds_write_b128 per pass
        #pragma unroll
        for (int p = 0; p < 4; ++p) {
            union { unsigned short u[8]; bf16x8 v; } pk;
            pk.u[0] = f2bf(a[p][0].x); pk.u[1] = f2bf(a[p][0].y);
            pk.u[2] = f2bf(a[p][0].z); pk.u[3] = f2bf(a[p][0].w);
            pk.u[4] = f2bf(a[p][1].x); pk.u[5] = f2bf(a[p][1].y);
            pk.u[6] = f2bf(a[p][1].z); pk.u[7] = f2bf(a[p][1].w);
            *reinterpret_cast<bf16x8*>(Awr + p * 4096) = pk.v;
        }
        // ---- B write: mask = mw / (1 + exp2(v1s*v2)), v1s pre-scaled
        #pragma unroll
        for (int p = 0; p < 2; ++p) {
            const float v2 = p ? v2r1 : v2r0;
            union { unsigned short u[8]; bf16x8 v; } pk;
            pk.u[0] = f2bf(w[p][0].x * __builtin_amdgcn_rcpf(1.0f + __builtin_amdgcn_exp2f(vv[0].x * v2)));
            pk.u[1] = f2bf(w[p][0].y * __builtin_amdgcn_rcpf(1.0f + __builtin_amdgcn_exp2f(vv[0].y * v2)));
            pk.u[2] = f2bf(w[p][0].z * __builtin_amdgcn_rcpf(1.0f + __builtin_amdgcn_exp2f(vv[0].z * v2)));
            pk.u[3] = f2bf(w[p][0].w * __builtin_amdgcn_rcpf(1.0f + __builtin_amdgcn_exp2f(vv[0].w * v2)));
            pk.u[4] = f2bf(w[p][1].x * __builtin_amdgcn_rcpf(1.0f + __builtin_amdgcn_exp2f(vv[1].x * v2)));
            pk.u[5] = f2bf(w[p][1].y * __builtin_amdgcn_rcpf(1.0f + __builtin_amdgcn_exp2f(vv[1].y * v2)));
            pk.u[6] = f2bf(w[p][1].z * __builtin_amdgcn_rcpf(1.0f + __builtin_amdgcn_exp2f(vv[1].z * v2)));
            pk.u[7] = f2bf(w[p][1].w * __builtin_amdgcn_rcpf(1.0f + __builtin_amdgcn_exp2f(vv[1].w * v2)));
            *reinterpret_cast<bf16x8*>(Bwr + p * 4096) = pk.v;
        }
        if (kt < 15) LOADS((kt + 1) * 64);      // next tile in flight under MFMA
        asm volatile("s_waitcnt lgkmcnt(0)" ::: "memory");
        __builtin_amdgcn_s_barrier();           // LDS writes visible
        // ---- compute: 2 k-halves x 16 MFMA
        #pragma unroll
        for (int kh = 0; kh < 2; ++kh) {
            const int kslot = (lane >> 4) + kh * 4;
            bf16x8 af[4], bq[4];
            #pragma unroll
            for (int m2 = 0; m2 < 4; ++m2) {
                int r = wr + m2 * 16 + (lane & 15);
                af[m2] = *reinterpret_cast<const bf16x8*>(
                    As + r * 64 + ((kslot ^ (r & 7)) << 3));
            }
            #pragma unroll
            for (int n2 = 0; n2 < 4; ++n2) {
                int r = wc + n2 * 16 + (lane & 15);
                bq[n2] = *reinterpret_cast<const bf16x8*>(
                    Bs + r * 64 + ((kslot ^ (r & 7)) << 3));
            }
            #pragma unroll
            for (int m2 = 0; m2 < 4; ++m2)
                #pragma unroll
                for (int n2 = 0; n2 < 4; ++n2)
                    acc[m2][n2] = __builtin_amdgcn_mfma_f32_16x16x32_bf16(
                        af[m2], bq[n2], acc[m2][n2], 0, 0, 0);
        }
        __builtin_amdgcn_s_barrier();           // compute done before overwrite
    }
#undef LOADS

    // epilogue: C/D layout col=lane&15 (f), row=(lane>>4)*4+r (s)
    const int col = lane & 15, rg = (lane >> 4) * 4;
    float bias[4];
    #pragma unroll
    for (int n2 = 0; n2 < 4; ++n2) bias[n2] = mb[f0 + wc + n2 * 16 + col];
    #pragma unroll
    for (int m2 = 0; m2 < 4; ++m2)
        #pragma unroll
        for (int n2 = 0; n2 < 4; ++n2)
            #pragma unroll
            for (int r = 0; r < 4; ++r) {
                int srow = s0 + wr + m2 * 16 + rg + r;
                out[(size_t)srow * (B_ * F_) + b * F_ + f0 + wc + n2 * 16 + col]
                    = acc[m2][n2][r] + bias[n2];
            }
}

extern "C" void kernel_launch(void* const* d_in, const int* in_sizes, int n_in,
                              void* d_out, int out_size, void* d_ws, size_t ws_size,
                              hipStream_t stream) {
    const float* x   = (const float*)d_in[0];
    const float* w1w = (const float*)d_in[1];
    const float* w1b = (const float*)d_in[2];
    const float* w2w = (const float*)d_in[3];
    const float* w2b = (const float*)d_in[4];
    const float* mw  = (const float*)d_in[5];
    const float* mb  = (const float*)d_in[6];
    float* outp = (float*)d_out;
    float* vbuf = (float*)d_ws;                 // [32][2048] f32 = 256 KB

    hipMemsetAsync(vbuf, 0, B_ * 2048 * sizeof(float), stream);
    vker<<<256, 256, 0, stream>>>(x, w1w, w1b, w2w, w2b, vbuf);
    fused<<<512, 512, 0, stream>>>(x, mw, mb, vbuf, outp);
}

// Round 12
// 201.405 us; speedup vs baseline: 1.2722x; 1.0619x over previous
//
#include <hip/hip_runtime.h>
#include <hip/hip_bf16.h>

#define S_ 512
#define B_ 32
#define D_ 1024
#define F_ 1024

typedef float f32x4 __attribute__((ext_vector_type(4)));
typedef short bf16x8 __attribute__((ext_vector_type(8)));
typedef unsigned u32x4 __attribute__((ext_vector_type(4)));

static __device__ __forceinline__ unsigned cvtpk(float lo, float hi) {
    unsigned r;
    asm("v_cvt_pk_bf16_f32 %0, %1, %2" : "=v"(r) : "v"(lo), "v"(hi));
    return r;
}

// ---------------- Kernel V: v = x0 @ [w1|w2]^T + bias, into vbuf[B][2048] ----
// v1 half (fg<1024) pre-scaled by -log2(e) so fused can use exp2 directly.
__global__ __launch_bounds__(256) void vker(
    const float* __restrict__ x,
    const float* __restrict__ w1w, const float* __restrict__ w1b,
    const float* __restrict__ w2w, const float* __restrict__ w2b,
    float* __restrict__ vbuf)
{
    __shared__ float xs[B_][132];
    __shared__ float wst[64][132];
    int fb = blockIdx.x & 31;
    int ks = blockIdx.x >> 5;
    int k0 = ks * 128;
    int t  = threadIdx.x;
    const float* w = (fb < 16) ? w1w : w2w;
    int fbase = (fb < 16) ? fb * 64 : (fb - 16) * 64;

    #pragma unroll
    for (int i = 0; i < 4; ++i) {
        int q = t + 256 * i;
        int row = q >> 5, c4 = (q & 31) * 4;
        float4 v = *reinterpret_cast<const float4*>(x + (size_t)row * D_ + k0 + c4);
        *reinterpret_cast<float4*>(&xs[row][c4]) = v;
    }
    #pragma unroll
    for (int i = 0; i < 8; ++i) {
        int q = t + 256 * i;
        int row = q >> 5, c4 = (q & 31) * 4;
        float4 v = *reinterpret_cast<const float4*>(w + (size_t)(fbase + row) * D_ + k0 + c4);
        *reinterpret_cast<float4*>(&wst[row][c4]) = v;
    }
    __syncthreads();

    int b   = t >> 3;
    int fl0 = t & 7;
    float acc[8] = {0,0,0,0,0,0,0,0};
    for (int k4 = 0; k4 < 32; ++k4) {
        float4 xv = *reinterpret_cast<const float4*>(&xs[b][k4 * 4]);
        #pragma unroll
        for (int j = 0; j < 8; ++j) {
            float4 wv = *reinterpret_cast<const float4*>(&wst[fl0 + 8 * j][k4 * 4]);
            acc[j] += xv.x * wv.x + xv.y * wv.y + xv.z * wv.z + xv.w * wv.w;
        }
    }
    #pragma unroll
    for (int j = 0; j < 8; ++j) {
        int fg = fb * 64 + fl0 + 8 * j;
        float v = acc[j];
        if (ks == 0) v += (fg < 1024) ? w1b[fg] : w2b[fg - 1024];
        if (fg < 1024) v *= -1.44269504088896f;   // fold -log2(e) into v1
        atomicAdd(&vbuf[b * 2048 + fg], v);
    }
}

// ---------------- xcvt: x[S][B][D] f32 -> xb[B][S][D'] bf16, chunk-swizzled --
// Within each 64-elem K-slice, slot c holds original chunk c^(s&7), so the
// GEMM can global_load_lds linearly and read with the XOR swizzle.
__global__ __launch_bounds__(256) void xcvt(
    const float* __restrict__ x, unsigned short* __restrict__ xb)
{
    int g = blockIdx.x * 256 + threadIdx.x;   // 2,097,152 chunks of 8
    int c  = g & 7;
    int kt = (g >> 3) & 15;
    int s  = (g >> 7) & 511;
    int b  = g >> 16;
    const float* src = x + (((size_t)(s * B_ + b)) << 10) + kt * 64 + ((c ^ (s & 7)) << 3);
    float4 a0 = *reinterpret_cast<const float4*>(src);
    float4 a1 = *reinterpret_cast<const float4*>(src + 4);
    u32x4 pk = { cvtpk(a0.x, a0.y), cvtpk(a0.z, a0.w),
                 cvtpk(a1.x, a1.y), cvtpk(a1.z, a1.w) };
    *reinterpret_cast<u32x4*>(xb + ((size_t)g << 3)) = pk;
}

// ---------------- mwcvt: mw f32 -> bf16, plain layout -----------------------
__global__ __launch_bounds__(256) void mwcvt(
    const float* __restrict__ mw, unsigned short* __restrict__ mwb)
{
    int g = blockIdx.x * 256 + threadIdx.x;   // 131,072 chunks of 8
    const float* src = mw + ((size_t)g << 3);
    float4 a0 = *reinterpret_cast<const float4*>(src);
    float4 a1 = *reinterpret_cast<const float4*>(src + 4);
    u32x4 pk = { cvtpk(a0.x, a0.y), cvtpk(a0.z, a0.w),
                 cvtpk(a1.x, a1.y), cvtpk(a1.z, a1.w) };
    *reinterpret_cast<u32x4*>(mwb + ((size_t)g << 3)) = pk;
}

// ---------------- fused2: out[s,b,f] = sum_d x*sigmoid(v1*v2)*mw + mb -------
// tile 256s x 128f, 512 thr = 8 waves. A: global_load_lds from pre-swizzled
// bf16 xb (zero VALU). B: reg-staged sigmoid mask from bf16 mwb, cvt_pk pack.
__global__ __launch_bounds__(512) void fused2(
    const unsigned short* __restrict__ xb,
    const unsigned short* __restrict__ mwb,
    const float* __restrict__ mb, const float* __restrict__ vbuf,
    float* __restrict__ out)
{
    __shared__ __align__(16) unsigned short As[256 * 64];
    __shared__ __align__(16) unsigned short Bs[128 * 64];
    __shared__ float v2s[128];

    const int bid = blockIdx.x;
    const int b   = (bid & 7) + ((bid >> 3) & 3) * 8;   // XCD swizzle
    const int rem = bid >> 5;
    const int f0  = (rem & 7) * 128;
    const int s0  = (rem >> 3) * 256;

    const int tid  = threadIdx.x;
    const int lane = tid & 63, wid = tid >> 6;
    const int wr = (wid >> 1) * 64;
    const int wc = (wid & 1) * 64;

    if (tid < 128) v2s[tid] = vbuf[b * 2048 + 1024 + f0 + tid];

    // A-DMA: round p covers rows p*64 + wid*8 + (lane>>3), 16B chunk lane&7
    const unsigned short* adma = xb
        + ((size_t)(b * S_ + s0 + wid * 8 + (lane >> 3))) * D_ + ((lane & 7) << 3);
    unsigned short* alds = As + (wid * 8) * 64;

    // B staging: rows rbase, rbase+64; chunk c8
    const int rbase = tid >> 3;
    const int c8    = tid & 7;
    const unsigned short* wpt = mwb + (size_t)(f0 + rbase) * D_ + (c8 << 3);
    const float* vpt = vbuf + b * 2048 + (c8 << 3);
    unsigned short* Bwr = Bs + rbase * 64 + ((c8 ^ (rbase & 7)) << 3);

    f32x4 acc[4][4] = {};
    bf16x8 mwv0, mwv1;
    float4 vva, vvb;

    // prologue: B-regs for kt=0
    mwv0 = *reinterpret_cast<const bf16x8*>(wpt);
    mwv1 = *reinterpret_cast<const bf16x8*>(wpt + 64 * D_);
    vva  = *reinterpret_cast<const float4*>(vpt);
    vvb  = *reinterpret_cast<const float4*>(vpt + 4);
    __syncthreads();                      // v2s visible (also drains prologue)
    const float v2r0 = v2s[rbase];
    const float v2r1 = v2s[rbase + 64];

    for (int kt = 0; kt < 16; ++kt) {
        const int k0 = kt * 64;
        // (1) A-DMA for this K-tile (LDS released by prev end-barrier)
        #pragma unroll
        for (int p = 0; p < 4; ++p)
            __builtin_amdgcn_global_load_lds(
                (const __attribute__((address_space(1))) void*)(adma + (size_t)p * (64 * D_) + k0),
                (__attribute__((address_space(3))) void*)(alds + p * 4096),
                16, 0, 0);
        __builtin_amdgcn_sched_barrier(0);   // pin B-prefetch below DMA issues
        // (2) B mask compute + swizzled ds_write (regs from prev prefetch)
        {
            union { bf16x8 v; unsigned short u[8]; } m0, m1;
            m0.v = mwv0; m1.v = mwv1;
            float vf[8] = { vva.x, vva.y, vva.z, vva.w, vvb.x, vvb.y, vvb.z, vvb.w };
            float p0[8], p1[8];
            #pragma unroll
            for (int j = 0; j < 8; ++j) {
                float w0 = __uint_as_float((unsigned)(unsigned short)m0.u[j] << 16);
                float w1 = __uint_as_float((unsigned)(unsigned short)m1.u[j] << 16);
                float e0 = __builtin_amdgcn_exp2f(vf[j] * v2r0);
                float e1 = __builtin_amdgcn_exp2f(vf[j] * v2r1);
                p0[j] = w0 * __builtin_amdgcn_rcpf(1.0f + e0);
                p1[j] = w1 * __builtin_amdgcn_rcpf(1.0f + e1);
            }
            u32x4 o0 = { cvtpk(p0[0], p0[1]), cvtpk(p0[2], p0[3]),
                         cvtpk(p0[4], p0[5]), cvtpk(p0[6], p0[7]) };
            u32x4 o1 = { cvtpk(p1[0], p1[1]), cvtpk(p1[2], p1[3]),
                         cvtpk(p1[4], p1[5]), cvtpk(p1[6], p1[7]) };
            *reinterpret_cast<u32x4*>(Bwr) = o0;
            *reinterpret_cast<u32x4*>(Bwr + 64 * 64) = o1;
        }
        // (3) prefetch B-regs for next K-tile (wraps at end; harmless)
        {
            const int k1 = ((kt + 1) & 15) * 64;
            mwv0 = *reinterpret_cast<const bf16x8*>(wpt + k1);
            mwv1 = *reinterpret_cast<const bf16x8*>(wpt + 64 * D_ + k1);
            vva  = *reinterpret_cast<const float4*>(vpt + k1);
            vvb  = *reinterpret_cast<const float4*>(vpt + k1 + 4);
        }
        // (4) drain the 4 A-DMAs (B-prefetch stays in flight) + ds_writes
        asm volatile("s_waitcnt vmcnt(4) lgkmcnt(0)" ::: "memory");
        __builtin_amdgcn_s_barrier();
        // (5) compute: 2 k-halves x 16 MFMA
        #pragma unroll
        for (int kh = 0; kh < 2; ++kh) {
            const int kslot = (lane >> 4) + kh * 4;
            bf16x8 af[4], bq[4];
            #pragma unroll
            for (int m2 = 0; m2 < 4; ++m2) {
                int r = wr + m2 * 16 + (lane & 15);
                af[m2] = *reinterpret_cast<const bf16x8*>(
                    As + r * 64 + ((kslot ^ (r & 7)) << 3));
            }
            #pragma unroll
            for (int n2 = 0; n2 < 4; ++n2) {
                int r = wc + n2 * 16 + (lane & 15);
                bq[n2] = *reinterpret_cast<const bf16x8*>(
                    Bs + r * 64 + ((kslot ^ (r & 7)) << 3));
            }
            #pragma unroll
            for (int m2 = 0; m2 < 4; ++m2)
                #pragma unroll
                for (int n2 = 0; n2 < 4; ++n2)
                    acc[m2][n2] = __builtin_amdgcn_mfma_f32_16x16x32_bf16(
                        af[m2], bq[n2], acc[m2][n2], 0, 0, 0);
        }
        __builtin_amdgcn_s_barrier();    // compute done before next overwrite
    }

    // epilogue: C/D layout col=lane&15 (f), row=(lane>>4)*4+r (s)
    const int col = lane & 15, rg = (lane >> 4) * 4;
    float bias[4];
    #pragma unroll
    for (int n2 = 0; n2 < 4; ++n2) bias[n2] = mb[f0 + wc + n2 * 16 + col];
    #pragma unroll
    for (int m2 = 0; m2 < 4; ++m2)
        #pragma unroll
        for (int n2 = 0; n2 < 4; ++n2)
            #pragma unroll
            for (int r = 0; r < 4; ++r) {
                int srow = s0 + wr + m2 * 16 + rg + r;
                out[(size_t)srow * (B_ * F_) + b * F_ + f0 + wc + n2 * 16 + col]
                    = acc[m2][n2][r] + bias[n2];
            }
}

extern "C" void kernel_launch(void* const* d_in, const int* in_sizes, int n_in,
                              void* d_out, int out_size, void* d_ws, size_t ws_size,
                              hipStream_t stream) {
    const float* x   = (const float*)d_in[0];
    const float* w1w = (const float*)d_in[1];
    const float* w1b = (const float*)d_in[2];
    const float* w2w = (const float*)d_in[3];
    const float* w2b = (const float*)d_in[4];
    const float* mw  = (const float*)d_in[5];
    const float* mb  = (const float*)d_in[6];
    float* outp = (float*)d_out;

    float* vbuf = (float*)d_ws;                                               // 256 KB
    unsigned short* xbp  = (unsigned short*)((char*)d_ws + ((size_t)1 << 20)); // 32 MB
    unsigned short* mwbp = (unsigned short*)((char*)d_ws + ((size_t)35 << 20)); // 2 MB

    hipMemsetAsync(vbuf, 0, B_ * 2048 * sizeof(float), stream);
    vker<<<256, 256, 0, stream>>>(x, w1w, w1b, w2w, w2b, vbuf);
    xcvt<<<8192, 256, 0, stream>>>(x, xbp);
    mwcvt<<<512, 256, 0, stream>>>(mw, mwbp);
    fused2<<<512, 512, 0, stream>>>(xbp, mwbp, mb, vbuf, outp);
}